// Round 5
// baseline (2156.043 us; speedup 1.0000x reference)
//
#include <hip/hip_runtime.h>
#include <hip/hip_cooperative_groups.h>

namespace cg = cooperative_groups;

#define B_ 8
#define C_ 3
#define H_ 256
#define W_ 256
#define HID_ 32
#define HW_ (H_*W_)            // 65536
#define N_ (B_*H_*W_)          // 524288
#define K01_ 0xBDCCCCCDu       // fkey(0.1f)
#define GRID_LOOP 1024         // 4 blocks/CU on 256 CUs -> co-resident

__device__ __forceinline__ unsigned fkey(float f){
  unsigned u = __float_as_uint(f);
  return (u & 0x80000000u) ? ~u : (u | 0x80000000u);
}

// conv backbone -> per-pixel hidden features as initial region sums.
// LDS-staged so the fsum store is fully coalesced (16B/lane consecutive).
// Also: labels=iota, cnt=1, psum=center pixel, mkA=0 (iteration-0 buffer).
__global__ __launch_bounds__(256) void k_conv_init(const float* __restrict__ img,
    const float* __restrict__ cw, const float* __restrict__ cb,
    float* __restrict__ fsum, int* __restrict__ labels,
    float* __restrict__ cnt, float* __restrict__ psum,
    unsigned long long* __restrict__ mkA){
  __shared__ float w_s[HID_*C_*9];
  __shared__ float b_s[HID_];
  __shared__ float stage[256*33];          // pad 33: (t+d)%32 banks, 2-way free
  for (int t = threadIdx.x; t < HID_*C_*9; t += blockDim.x) w_s[t] = cw[t];
  if (threadIdx.x < HID_) b_s[threadIdx.x] = cb[threadIdx.x];
  __syncthreads();
  int i = blockIdx.x*blockDim.x + threadIdx.x;
  if (i >= N_) return;
  int b = i >> 16; int rem = i & (HW_-1); int h = rem >> 8; int w = rem & (W_-1);
  float patch[C_*9];
  #pragma unroll
  for (int ci=0; ci<C_; ++ci){
    const float* ip = img + (size_t)(b*C_+ci)*HW_;
    #pragma unroll
    for (int kh=0; kh<3; ++kh){
      int hh = h + kh - 1;
      #pragma unroll
      for (int kw=0; kw<3; ++kw){
        int ww = w + kw - 1;
        float v = 0.f;
        if (hh >= 0 && hh < H_ && ww >= 0 && ww < W_) v = ip[hh*W_+ww];
        patch[ci*9+kh*3+kw] = v;
      }
    }
  }
  #pragma unroll 4
  for (int oc=0; oc<HID_; ++oc){
    float a = b_s[oc];
    const float* ws = w_s + oc*C_*9;
    #pragma unroll
    for (int t=0; t<C_*9; ++t) a += patch[t]*ws[t];
    stage[threadIdx.x*33 + oc] = a;
  }
  __syncthreads();
  // coalesced block-contiguous write: 2048 float4 per block
  float4* dst = (float4*)(fsum + (size_t)blockIdx.x*256*HID_);
  #pragma unroll
  for (int k=0; k<8; ++k){
    int idx = k*256 + threadIdx.x;
    int p = idx >> 3, e = (idx & 7)*4;
    const float* s = stage + p*33 + e;
    dst[idx] = make_float4(s[0], s[1], s[2], s[3]);
  }
  labels[i] = i;
  cnt[i] = 1.0f;
  mkA[i] = 0ULL;
  #pragma unroll
  for (int c=0; c<C_; ++c) psum[(size_t)i*C_+c] = patch[c*9+4];  // center pixel
}

// fused sim+best for one pixel's right/down edges.
// packed scatter-argmax: (fkey(sim)<<32)|neighbor_region. High-word equality
// == float equality, so low-word max == reference's "max rb among argmax".
__device__ __forceinline__ void simbest_body(int i, bool it0,
    const int* __restrict__ labels, const float* __restrict__ fsum,
    const float* __restrict__ cnt, unsigned long long* __restrict__ mk){
  int rem = i & (HW_-1); int h = rem >> 8; int w = rem & (W_-1);
  int ri, rR, rD;
  if (it0){
    ri = i;
    rR = (w < W_-1) ? i+1  : ri;
    rD = (h < H_-1) ? i+W_ : ri;
  } else {
    ri = labels[i];
    rR = (w < W_-1) ? labels[i+1]  : ri;
    rD = (h < H_-1) ? labels[i+W_] : ri;
  }
  bool eR = (rR != ri), eD = (rD != ri);
  if (!eR && !eD) return;
  float rci = it0 ? 1.0f : 1.0f / cnt[ri];
  const float4* fi = (const float4*)(fsum + (size_t)ri*HID_);
  float4 mi[HID_/4];
  #pragma unroll
  for (int k=0; k<HID_/4; ++k){
    float4 v = fi[k];
    mi[k] = make_float4(v.x*rci, v.y*rci, v.z*rci, v.w*rci);
  }
  if (eR){
    float rcj = it0 ? 1.0f : 1.0f / cnt[rR];
    const float4* fj = (const float4*)(fsum + (size_t)rR*HID_);
    float d2 = 0.f;
    #pragma unroll
    for (int k=0; k<HID_/4; ++k){
      float4 v = fj[k];
      float tx = mi[k].x - v.x*rcj; float ty = mi[k].y - v.y*rcj;
      float tz = mi[k].z - v.z*rcj; float tw = mi[k].w - v.w*rcj;
      d2 += tx*tx + ty*ty + tz*tz + tw*tw;
    }
    unsigned long long sk = (unsigned long long)fkey(expf(-d2)) << 32;
    atomicMax(mk+ri, sk | (unsigned)rR);
    atomicMax(mk+rR, sk | (unsigned)ri);
  }
  if (eD){
    float rcj = it0 ? 1.0f : 1.0f / cnt[rD];
    const float4* fj = (const float4*)(fsum + (size_t)rD*HID_);
    float d2 = 0.f;
    #pragma unroll
    for (int k=0; k<HID_/4; ++k){
      float4 v = fj[k];
      float tx = mi[k].x - v.x*rcj; float ty = mi[k].y - v.y*rcj;
      float tz = mi[k].z - v.z*rcj; float tw = mi[k].w - v.w*rcj;
      d2 += tx*tx + ty*ty + tz*tz + tw*tw;
    }
    unsigned long long sk = (unsigned long long)fkey(expf(-d2)) << 32;
    atomicMax(mk+ri, sk | (unsigned)rD);
    atomicMax(mk+rD, sk | (unsigned)ri);
  }
}

// on-the-fly par2(x) chase to fixpoint; fold dying-root sums; relabel.
__device__ __forceinline__ void update_body(int i,
    const unsigned long long* __restrict__ mk, int* __restrict__ labels,
    float* __restrict__ fsum, float* __restrict__ psum, float* __restrict__ cnt){
  int l = labels[i];
  int x = l;
  for (int it = 0; it < (1<<20); ++it){
    unsigned long long m = mk[x];
    int p = ((unsigned)(m >> 32) > K01_) ? (int)(m & 0xffffffffu) : x;
    if (p == x) break;
    unsigned long long m2 = mk[p];
    int pp = ((unsigned)(m2 >> 32) > K01_) ? (int)(m2 & 0xffffffffu) : p;
    if (pp == x && x < p) break;     // broken 2-cycle: x is the root
    x = p;
  }
  if (l == i && x != i){             // dying root: fold into surviving root
    atomicAdd(cnt+x, cnt[i]);
    const float* s = fsum + (size_t)i*HID_;
    float* ds = fsum + (size_t)x*HID_;
    #pragma unroll
    for (int d=0; d<HID_; ++d) atomicAdd(ds+d, s[d]);
    const float* ps = psum + (size_t)i*C_;
    float* dp = psum + (size_t)x*C_;
    #pragma unroll
    for (int c=0; c<C_; ++c) atomicAdd(dp+c, ps[c]);
  }
  labels[i] = x;
}

// the whole 8-iteration merge loop in one cooperative kernel.
// phase A (simbest) / grid.sync / phase B (update + clear next mk) / grid.sync
__global__ __launch_bounds__(256, 4) void k_loop(int* __restrict__ labels,
    float* __restrict__ fsum, float* __restrict__ psum, float* __restrict__ cnt,
    unsigned long long* __restrict__ mkA, unsigned long long* __restrict__ mkB){
  cg::grid_group grid = cg::this_grid();
  const int nt = (int)(gridDim.x * blockDim.x);
  const int t0 = blockIdx.x*blockDim.x + threadIdx.x;
  for (int it = 0; it < 8; ++it){
    unsigned long long* mk  = (it & 1) ? mkB : mkA;
    unsigned long long* mkN = (it & 1) ? mkA : mkB;
    bool it0 = (it == 0);
    for (int i = t0; i < N_; i += nt)
      simbest_body(i, it0, labels, fsum, cnt, mk);
    grid.sync();
    for (int i = t0; i < N_; i += nt){
      mkN[i] = 0ULL;                 // pre-clear next iteration's buffer
      update_body(i, mk, labels, fsum, psum, cnt);
    }
    grid.sync();
  }
}

// finalize fused: per-pixel recompute of region feature at its root
// (root rows are few and L2-hot), mean injection, labels as float.
__global__ __launch_bounds__(256) void k_out(const int* __restrict__ labels,
      const float* __restrict__ img, const float* __restrict__ cnt,
      const float* __restrict__ fsum, const float* __restrict__ psum,
      const float* __restrict__ lw, const float* __restrict__ lb,
      float* __restrict__ out, float* __restrict__ outlab){
  __shared__ float lw_s[C_*HID_];
  __shared__ float lb_s[C_];
  for (int t = threadIdx.x; t < C_*HID_; t += blockDim.x) lw_s[t] = lw[t];
  if (threadIdx.x < C_) lb_s[threadIdx.x] = lb[threadIdx.x];
  __syncthreads();
  int i = blockIdx.x*blockDim.x + threadIdx.x;
  if (i >= N_) return;
  int l = labels[i];
  float rc = 1.0f / cnt[l];
  const float* s = fsum + (size_t)l*HID_;
  float rf[C_];
  #pragma unroll
  for (int cc=0; cc<C_; ++cc){
    float a = 0.f;
    const float* wv = lw_s + cc*HID_;
    #pragma unroll
    for (int d=0; d<HID_; ++d) a += (s[d]*rc)*wv[d];
    rf[cc] = (a + lb_s[cc]) - psum[(size_t)l*C_+cc]*rc;
  }
  int b = i >> 16; int rem = i & (HW_-1);
  const float* ip = img + (size_t)b*C_*HW_ + rem;
  #pragma unroll
  for (int cc=0; cc<C_; ++cc)
    out[(size_t)i*C_+cc] = ip[(size_t)cc*HW_] + rf[cc];
  outlab[i] = (float)l;
}

extern "C" void kernel_launch(void* const* d_in, const int* in_sizes, int n_in,
                              void* d_out, int out_size, void* d_ws, size_t ws_size,
                              hipStream_t stream) {
  const float* img = (const float*)d_in[0];
  const float* cw  = (const float*)d_in[1];
  const float* cb  = (const float*)d_in[2];
  const float* lw  = (const float*)d_in[3];
  const float* lb  = (const float*)d_in[4];

  char* ws = (char*)d_ws;
  size_t off = 0;
  auto alloc = [&](size_t bytes) -> void* {
    void* p = ws + off; off += (bytes + 255) & ~(size_t)255; return p;
  };
  float*              fsum   = (float*)              alloc((size_t)N_*HID_*4);
  float*              psum   = (float*)              alloc((size_t)N_*C_*4);
  float*              cnt    = (float*)              alloc((size_t)N_*4);
  unsigned long long* mkA    = (unsigned long long*) alloc((size_t)N_*8);
  unsigned long long* mkB    = (unsigned long long*) alloc((size_t)N_*8);
  int*                labels = (int*)                alloc((size_t)N_*4);

  dim3 blk(256);
  int gN = (N_ + 255) / 256;

  k_conv_init<<<gN, blk, 0, stream>>>(img, cw, cb, fsum, labels, cnt, psum, mkA);

  void* args[] = { (void*)&labels, (void*)&fsum, (void*)&psum, (void*)&cnt,
                   (void*)&mkA, (void*)&mkB };
  hipLaunchCooperativeKernel((void*)k_loop, dim3(GRID_LOOP), blk, args, 0, stream);

  float* out = (float*)d_out;
  k_out<<<gN, blk, 0, stream>>>(labels, img, cnt, fsum, psum, lw, lb,
                                out, out + (size_t)N_*C_);
}

// Round 6
// 315.949 us; speedup vs baseline: 6.8240x; 6.8240x over previous
//
#include <hip/hip_runtime.h>

#define B_ 8
#define C_ 3
#define H_ 256
#define W_ 256
#define HID_ 32
#define HW_ (H_*W_)            // 65536
#define N_ (B_*H_*W_)          // 524288
#define K01_ 0xBDCCCCCDu       // fkey(0.1f)
#define TILE_ 16
#define VPAD_ 33               // LDS row stride (floats) for conv vectors

__device__ __forceinline__ unsigned fkey(float f){
  unsigned u = __float_as_uint(f);
  return (u & 0x80000000u) ? ~u : (u | 0x80000000u);
}

// mk entry: [63:56]=tag(it+1) | [55:24]=fkey(sim) | [23:0]=neighbor id.
// atomicMax: newer tag always wins; same tag -> (key,id) lexicographic max,
// which is exactly the reference's "max rb among sim==maxsim" tie-break.
__device__ __forceinline__ unsigned long long pack_mk(unsigned tag, unsigned key, int id){
  return ((unsigned long long)tag << 56) | ((unsigned long long)key << 24) | (unsigned)id;
}

__device__ __forceinline__ void conv_at(const float* __restrict__ img,
    const float* __restrict__ w_s, const float* __restrict__ b_s,
    int b, int h, int w, float* acc){
  float patch[C_*9];
  #pragma unroll
  for (int ci=0; ci<C_; ++ci){
    const float* ip = img + (size_t)(b*C_+ci)*HW_;
    #pragma unroll
    for (int kh=0; kh<3; ++kh){
      int hh = h + kh - 1;
      #pragma unroll
      for (int kw=0; kw<3; ++kw){
        int ww = w + kw - 1;
        float v = 0.f;
        if (hh >= 0 && hh < H_ && ww >= 0 && ww < W_) v = ip[hh*W_+ww];
        patch[ci*9+kh*3+kw] = v;
      }
    }
  }
  #pragma unroll 4
  for (int oc=0; oc<HID_; ++oc){
    float a = b_s[oc];
    const float* ws = w_s + oc*C_*9;
    #pragma unroll
    for (int t=0; t<C_*9; ++t) a += patch[t]*ws[t];
    acc[oc] = a;
  }
}

// 16x16-tile conv + iteration-0 simbest fused. Computes 17x17 conv outputs
// (1-wide right/bottom halo recomputed) into LDS, writes fsum (coalesced,
// LDS-staged), labels=iota, cnt=1, psum=center pixel, and it0 edge sims
// (region features at it0 ARE the conv outputs; cnt==1 so no divides).
__global__ __launch_bounds__(256) void k_conv_init(const float* __restrict__ img,
    const float* __restrict__ cw, const float* __restrict__ cb,
    float* __restrict__ fsum, int* __restrict__ labels,
    float* __restrict__ cnt, float* __restrict__ psum,
    unsigned long long* __restrict__ mk){
  __shared__ float w_s[HID_*C_*9];
  __shared__ float b_s[HID_];
  __shared__ float vec[(TILE_+1)*(TILE_+1)*VPAD_];   // 289 rows x 33 floats
  for (int t = threadIdx.x; t < HID_*C_*9; t += blockDim.x) w_s[t] = cw[t];
  if (threadIdx.x < HID_) b_s[threadIdx.x] = cb[threadIdx.x];
  __syncthreads();

  int b  = blockIdx.x >> 8;          // 256 tiles per image
  int ti = blockIdx.x & 255;
  int h0 = (ti >> 4) * TILE_;
  int w0 = (ti & 15) * TILE_;
  int r  = threadIdx.x >> 4;         // 0..15
  int c  = threadIdx.x & 15;
  int h  = h0 + r, w = w0 + c;
  int i  = (b << 16) | (h << 8) | w;

  float acc[HID_];
  conv_at(img, w_s, b_s, b, h, w, acc);
  {
    float* vr = vec + (r*(TILE_+1)+c)*VPAD_;
    #pragma unroll
    for (int oc=0; oc<HID_; ++oc) vr[oc] = acc[oc];
  }
  // halo: threads 0..32 compute one extra position each
  if (threadIdx.x < 2*TILE_+1){
    int hr, hc;
    if (threadIdx.x < TILE_+1){ hr = threadIdx.x; hc = TILE_; }
    else                      { hr = TILE_; hc = threadIdx.x - (TILE_+1); }
    int hh = h0 + hr, hw = w0 + hc;
    if (hh < H_ && hw < W_){
      float hacc[HID_];
      conv_at(img, w_s, b_s, b, hh, hw, hacc);
      float* vr = vec + (hr*(TILE_+1)+hc)*VPAD_;
      #pragma unroll
      for (int oc=0; oc<HID_; ++oc) vr[oc] = hacc[oc];
    }
  }
  __syncthreads();

  // coalesced fsum store: tile pixels' rows are 16 contiguous 2KB runs
  {
    float4* dst = (float4*)fsum;
    #pragma unroll
    for (int k=0; k<8; ++k){
      int idx = k*256 + threadIdx.x;        // 0..2047 float4 slots in tile
      int pl  = idx >> 3;                   // local pixel 0..255
      int pr  = pl >> 4, pc = pl & 15;
      int e   = (idx & 7) * 4;
      const float* s = vec + (pr*(TILE_+1)+pc)*VPAD_ + e;
      int gi = (b << 16) | ((h0+pr) << 8) | (w0+pc);
      dst[(size_t)gi*(HID_/4) + (idx & 7)] = make_float4(s[0], s[1], s[2], s[3]);
    }
  }

  labels[i] = i;
  cnt[i] = 1.0f;
  {
    const float* ip = img + (size_t)b*C_*HW_ + (i & (HW_-1));
    #pragma unroll
    for (int cc=0; cc<C_; ++cc) psum[(size_t)i*C_+cc] = ip[(size_t)cc*HW_];
  }

  // it0 sims: right (i,i+1), down (i,i+W); tag = 1
  bool hasR = (w < W_-1), hasD = (h < H_-1);
  if (hasR){
    const float* vn = vec + (r*(TILE_+1)+(c+1))*VPAD_;
    float d2 = 0.f;
    #pragma unroll
    for (int k=0; k<HID_/4; ++k){
      float tx = acc[4*k]   - vn[4*k];
      float ty = acc[4*k+1] - vn[4*k+1];
      float tz = acc[4*k+2] - vn[4*k+2];
      float tw = acc[4*k+3] - vn[4*k+3];
      d2 += tx*tx + ty*ty + tz*tz + tw*tw;
    }
    unsigned key = fkey(expf(-d2));
    atomicMax(mk+i,   pack_mk(1u, key, i+1));
    atomicMax(mk+i+1, pack_mk(1u, key, i));
  }
  if (hasD){
    const float* vn = vec + ((r+1)*(TILE_+1)+c)*VPAD_;
    float d2 = 0.f;
    #pragma unroll
    for (int k=0; k<HID_/4; ++k){
      float tx = acc[4*k]   - vn[4*k];
      float ty = acc[4*k+1] - vn[4*k+1];
      float tz = acc[4*k+2] - vn[4*k+2];
      float tw = acc[4*k+3] - vn[4*k+3];
      d2 += tx*tx + ty*ty + tz*tz + tw*tw;
    }
    unsigned key = fkey(expf(-d2));
    atomicMax(mk+i,    pack_mk(1u, key, i+W_));
    atomicMax(mk+i+W_, pack_mk(1u, key, i));
  }
}

// general-iteration fused sim+best (tag = it+1); stale tags lose/ignored.
__global__ void k_simbest(const int* __restrict__ labels,
                          const float* __restrict__ fsum, const float* __restrict__ cnt,
                          unsigned long long* __restrict__ mk, unsigned tag){
  int i = blockIdx.x*blockDim.x + threadIdx.x;
  if (i >= N_) return;
  int rem = i & (HW_-1); int h = rem >> 8; int w = rem & (W_-1);
  int ri = labels[i];
  int rR = (w < W_-1) ? labels[i+1]  : ri;
  int rD = (h < H_-1) ? labels[i+W_] : ri;
  bool eR = (rR != ri), eD = (rD != ri);
  if (!eR && !eD) return;
  float rci = 1.0f / cnt[ri];
  const float4* fi = (const float4*)(fsum + (size_t)ri*HID_);
  float4 mi[HID_/4];
  #pragma unroll
  for (int k=0; k<HID_/4; ++k){
    float4 v = fi[k];
    mi[k] = make_float4(v.x*rci, v.y*rci, v.z*rci, v.w*rci);
  }
  if (eR){
    float rcj = 1.0f / cnt[rR];
    const float4* fj = (const float4*)(fsum + (size_t)rR*HID_);
    float d2 = 0.f;
    #pragma unroll
    for (int k=0; k<HID_/4; ++k){
      float4 v = fj[k];
      float tx = mi[k].x - v.x*rcj; float ty = mi[k].y - v.y*rcj;
      float tz = mi[k].z - v.z*rcj; float tw = mi[k].w - v.w*rcj;
      d2 += tx*tx + ty*ty + tz*tz + tw*tw;
    }
    unsigned key = fkey(expf(-d2));
    atomicMax(mk+ri, pack_mk(tag, key, rR));
    atomicMax(mk+rR, pack_mk(tag, key, ri));
  }
  if (eD){
    float rcj = 1.0f / cnt[rD];
    const float4* fj = (const float4*)(fsum + (size_t)rD*HID_);
    float d2 = 0.f;
    #pragma unroll
    for (int k=0; k<HID_/4; ++k){
      float4 v = fj[k];
      float tx = mi[k].x - v.x*rcj; float ty = mi[k].y - v.y*rcj;
      float tz = mi[k].z - v.z*rcj; float tw = mi[k].w - v.w*rcj;
      d2 += tx*tx + ty*ty + tz*tz + tw*tw;
    }
    unsigned key = fkey(expf(-d2));
    atomicMax(mk+ri, pack_mk(tag, key, rD));
    atomicMax(mk+rD, pack_mk(tag, key, ri));
  }
}

__device__ __forceinline__ int parent_dec(unsigned long long m, unsigned tag, int x){
  if ((unsigned)(m >> 56) != tag) return x;
  return ((unsigned)(m >> 24) > K01_) ? (int)(m & 0xFFFFFFu) : x;
}

// on-the-fly par2 chase to fixpoint from labels[i]; fold dying-root sums;
// relabel. Dying roots are read-only slots; adds target surviving roots only.
__global__ void k_update(const unsigned long long* __restrict__ mk, unsigned tag,
                         int* __restrict__ labels,
                         float* __restrict__ fsum, float* __restrict__ psum,
                         float* __restrict__ cnt){
  int i = blockIdx.x*blockDim.x + threadIdx.x;
  if (i >= N_) return;
  int l = labels[i];
  int x = l;
  for (int it = 0; it < (1<<20); ++it){
    int p = parent_dec(mk[x], tag, x);
    if (p == x) break;
    int pp = parent_dec(mk[p], tag, p);
    if (pp == x && x < p) break;     // broken 2-cycle: x is the root
    x = p;
  }
  if (l == i && x != i){             // dying root: fold into surviving root
    atomicAdd(cnt+x, cnt[i]);
    const float* s = fsum + (size_t)i*HID_;
    float* ds = fsum + (size_t)x*HID_;
    #pragma unroll
    for (int d=0; d<HID_; ++d) atomicAdd(ds+d, s[d]);
    const float* ps = psum + (size_t)i*C_;
    float* dp = psum + (size_t)x*C_;
    #pragma unroll
    for (int c=0; c<C_; ++c) atomicAdd(dp+c, ps[c]);
  }
  labels[i] = x;
}

// finalize fused: per-pixel recompute of region feature at its root
// (root rows are few and L2-hot), mean injection, labels as float.
__global__ __launch_bounds__(256) void k_out(const int* __restrict__ labels,
      const float* __restrict__ img, const float* __restrict__ cnt,
      const float* __restrict__ fsum, const float* __restrict__ psum,
      const float* __restrict__ lw, const float* __restrict__ lb,
      float* __restrict__ out, float* __restrict__ outlab){
  __shared__ float lw_s[C_*HID_];
  __shared__ float lb_s[C_];
  for (int t = threadIdx.x; t < C_*HID_; t += blockDim.x) lw_s[t] = lw[t];
  if (threadIdx.x < C_) lb_s[threadIdx.x] = lb[threadIdx.x];
  __syncthreads();
  int i = blockIdx.x*blockDim.x + threadIdx.x;
  if (i >= N_) return;
  int l = labels[i];
  float rc = 1.0f / cnt[l];
  const float* s = fsum + (size_t)l*HID_;
  float rf[C_];
  #pragma unroll
  for (int cc=0; cc<C_; ++cc){
    float a = 0.f;
    const float* wv = lw_s + cc*HID_;
    #pragma unroll
    for (int d=0; d<HID_; ++d) a += (s[d]*rc)*wv[d];
    rf[cc] = (a + lb_s[cc]) - psum[(size_t)l*C_+cc]*rc;
  }
  int b = i >> 16; int rem = i & (HW_-1);
  const float* ip = img + (size_t)b*C_*HW_ + rem;
  #pragma unroll
  for (int cc=0; cc<C_; ++cc)
    out[(size_t)i*C_+cc] = ip[(size_t)cc*HW_] + rf[cc];
  outlab[i] = (float)l;
}

extern "C" void kernel_launch(void* const* d_in, const int* in_sizes, int n_in,
                              void* d_out, int out_size, void* d_ws, size_t ws_size,
                              hipStream_t stream) {
  const float* img = (const float*)d_in[0];
  const float* cw  = (const float*)d_in[1];
  const float* cb  = (const float*)d_in[2];
  const float* lw  = (const float*)d_in[3];
  const float* lb  = (const float*)d_in[4];

  char* ws = (char*)d_ws;
  size_t off = 0;
  auto alloc = [&](size_t bytes) -> void* {
    void* p = ws + off; off += (bytes + 255) & ~(size_t)255; return p;
  };
  float*              fsum   = (float*)              alloc((size_t)N_*HID_*4);
  float*              psum   = (float*)              alloc((size_t)N_*C_*4);
  float*              cnt    = (float*)              alloc((size_t)N_*4);
  unsigned long long* mk     = (unsigned long long*) alloc((size_t)N_*8);
  int*                labels = (int*)                alloc((size_t)N_*4);

  dim3 blk(256);
  int gN = (N_ + 255) / 256;

  hipMemsetAsync(mk, 0, (size_t)N_*8, stream);   // clear 0xAA poison once
  k_conv_init<<<2048, blk, 0, stream>>>(img, cw, cb, fsum, labels, cnt, psum, mk);
  k_update<<<gN, blk, 0, stream>>>(mk, 1u, labels, fsum, psum, cnt);

  for (int it = 1; it < 8; ++it) {
    k_simbest<<<gN, blk, 0, stream>>>(labels, fsum, cnt, mk, (unsigned)(it+1));
    k_update<<<gN, blk, 0, stream>>>(mk, (unsigned)(it+1), labels, fsum, psum, cnt);
  }

  float* out = (float*)d_out;
  k_out<<<gN, blk, 0, stream>>>(labels, img, cnt, fsum, psum, lw, lb,
                                out, out + (size_t)N_*C_);
}